// Round 16
// baseline (218.137 us; speedup 1.0000x reference)
//
#include <hip/hip_runtime.h>
#include <hip/hip_fp16.h>
#include <cstdint>
#include <cstddef>

#define DIM_IN 128
#define DIM_HID 64
#define MS_TILE 4096      // edges per multisplit tile (one WG per tile)
#define BSH 8             // bin shift: 256-node bins
#define BINSZ 256
#define MAXNB 512
#define MAXT 1024         // max tiles per LDS segment-chunk in fillA2
#define CAPL 10240        // LDS stage (40KB); bin mean 8184, ~22 sigma headroom

// native clang vectors (nontemporal builtins reject HIP_vector_type classes)
typedef int v2i __attribute__((ext_vector_type(2)));

// ---------- tile-major multisplit: LDS counting sort, ALL writes coalesced ----------
// R15 post-mortem: bin-major scattered writes (3.2M x 4B) were the cost in both
// msplit variants. Here each WG sorts its tile in LDS and writes its OWN
// contiguous 16KB window of `sorted` + a 392-int offset-table row. No global
// atomics, no overflow path (every edge has a deterministic slot).
__global__ __launch_bounds__(256) void k_msplit4(const int* __restrict__ eidx,
                                                 unsigned int* __restrict__ sorted,
                                                 int* __restrict__ offs,
                                                 int E, int NB) {
    __shared__ int hist[MAXNB], scanb[MAXNB], s4[128];
    __shared__ int stF;
    int t = threadIdx.x;
    if (t == 0) {           // int32 vs int64 detect (odd words of first 64 i64 all 0)
        int o = 0;
        for (int j = 1; j < 128; j += 2) o |= eidx[j];
        stF = (o == 0) ? 2 : 1;
    }
    hist[t] = 0; hist[t + 256] = 0;
    __syncthreads();
    int st = stF;

    int tile = blockIdx.x;
    int e0 = tile * MS_TILE;
    int e1 = min(e0 + MS_TILE, E);

    unsigned int words[16];
    int bins[16];
#pragma unroll
    for (int j = 0; j < 16; j++) {
        int e = e0 + t + 256 * j;
        if (e < e1) {
            int s, d;
            if (st == 2) {
                v2i a = __builtin_nontemporal_load((const v2i*)eidx + e);
                v2i b = __builtin_nontemporal_load((const v2i*)eidx + E + e);
                s = a.x; d = b.x;
            } else {
                s = __builtin_nontemporal_load(&eidx[e]);
                d = __builtin_nontemporal_load(&eidx[E + e]);
            }
            words[j] = ((unsigned int)s << BSH) | (unsigned int)(d & (BINSZ - 1));
            bins[j] = d >> BSH;
            atomicAdd(&hist[bins[j]], 1);
        } else {
            bins[j] = -1;
        }
    }
    __syncthreads();
    // 2-level exclusive scan over 512 entries (hist[NB..511] are 0)
    if (t < 128)
        s4[t] = hist[4 * t] + hist[4 * t + 1] + hist[4 * t + 2] + hist[4 * t + 3];
    __syncthreads();
    if (t == 0) {
        int run = 0;
        for (int b = 0; b < 128; b++) { int v = s4[b]; s4[b] = run; run += v; }
    }
    __syncthreads();
    if (t < 128) {
        int r = s4[t];
#pragma unroll
        for (int j = 0; j < 4; j++) { scanb[4 * t + j] = r; r += hist[4 * t + j]; }
    }
    __syncthreads();
    // offset-table row (coalesced): offs[tile][b], b=0..NB (scanb[NB]=tile count)
    for (int b = t; b <= NB; b += 256)
        offs[(size_t)tile * (NB + 1) + b] = scanb[b];
    hist[t] = 0; hist[t + 256] = 0;   // reuse as rank counters
    __syncthreads();
#pragma unroll
    for (int j = 0; j < 16; j++) {
        if (bins[j] >= 0) {
            int r = atomicAdd(&hist[bins[j]], 1);
            sorted[e0 + scanb[bins[j]] + r] = words[j];   // own 16KB window
        }
    }
}

// ---------- per-bin totals from the offset table ----------
__global__ __launch_bounds__(256) void k_binsum(const int* __restrict__ offs,
                                                int* __restrict__ binTot,
                                                int ntiles, int NB) {
    __shared__ int sh[256];
    int b = blockIdx.x;
    int t = threadIdx.x;
    int sum = 0;
    for (int T = t; T < ntiles; T += 256)
        sum += offs[(size_t)T * (NB + 1) + b + 1] - offs[(size_t)T * (NB + 1) + b];
    sh[t] = sum;
    __syncthreads();
    for (int d = 128; d > 0; d >>= 1) {
        if (t < d) sh[t] += sh[t + d];
        __syncthreads();
    }
    if (t == 0) binTot[b] = sh[0];
}

// ---------- exclusive scan of bin totals -> binBase ----------
__global__ __launch_bounds__(512) void k_binscan(const int* __restrict__ binTot,
                                                 int* __restrict__ binBase, int NB) {
    __shared__ int sh[512];
    int t = threadIdx.x;
    int v = (t < NB) ? binTot[t] : 0;
    sh[t] = v;
    __syncthreads();
    for (int d = 1; d < 512; d <<= 1) {
        int add = (t >= d) ? sh[t - d] : 0;
        __syncthreads();
        sh[t] += add;
        __syncthreads();
    }
    if (t < NB) binBase[t] = sh[t] - v;
}

// ---------- fused fill from tile segments: hist -> offsets/dinv; stage -> csr ----------
__global__ __launch_bounds__(256) void k_fillA2(const unsigned int* __restrict__ sorted,
                                                const int* __restrict__ offs,
                                                const int* __restrict__ binBase,
                                                int* __restrict__ offsets,
                                                float* __restrict__ dinv,
                                                int* __restrict__ csr,
                                                int ntiles, int NB, int N) {
    __shared__ int segLo[MAXT], segHi[MAXT];
    __shared__ int hist[BINSZ], scanS[BINSZ], curL[BINSZ];
    __shared__ unsigned int stage[CAPL];
    int b = blockIdx.x;
    int t = threadIdx.x;
    int g0 = b << BSH;
    int g = g0 + t;

    hist[t] = 0;
    __syncthreads();
    // pass 1: degree histogram over this bin's segments
    for (int T0 = 0; T0 < ntiles; T0 += MAXT) {
        int tc = min(MAXT, ntiles - T0);
        for (int T = t; T < tc; T += 256) {
            segLo[T] = offs[(size_t)(T0 + T) * (NB + 1) + b];
            segHi[T] = offs[(size_t)(T0 + T) * (NB + 1) + b + 1];
        }
        __syncthreads();
        for (int T = t; T < tc; T += 256) {
            const unsigned int* p = sorted + (size_t)(T0 + T) * MS_TILE;
            for (int i = segLo[T]; i < segHi[T]; i++)
                atomicAdd(&hist[p[i] & (BINSZ - 1)], 1);
        }
        __syncthreads();
    }
    int h = hist[t];
    scanS[t] = h;
    __syncthreads();
    for (int d = 1; d < 256; d <<= 1) {
        int add = (t >= d) ? scanS[t - d] : 0;
        __syncthreads();
        scanS[t] += add;
        __syncthreads();
    }
    int excl = scanS[t] - h;
    int gbase = binBase[b];
    if (g < N) {
        offsets[g] = gbase + excl;
        dinv[g] = rsqrtf((float)(h + 1));
    }
    if (t == 255) offsets[min(g0 + BINSZ, N)] = gbase + scanS[255];  // race-benign dup
    curL[t] = excl;
    __syncthreads();

    // pass 2: place into LDS stage, then coalesced flush
    for (int T0 = 0; T0 < ntiles; T0 += MAXT) {
        int tc = min(MAXT, ntiles - T0);
        for (int T = t; T < tc; T += 256) {
            segLo[T] = offs[(size_t)(T0 + T) * (NB + 1) + b];
            segHi[T] = offs[(size_t)(T0 + T) * (NB + 1) + b + 1];
        }
        __syncthreads();
        for (int T = t; T < tc; T += 256) {
            const unsigned int* p = sorted + (size_t)(T0 + T) * MS_TILE;
            for (int i = segLo[T]; i < segHi[T]; i++) {
                unsigned int w = p[i];
                int pos = atomicAdd(&curL[w & (BINSZ - 1)], 1);
                if (pos < CAPL) stage[pos] = w >> BSH;
                else csr[gbase + pos] = (int)(w >> BSH);   // ~22 sigma: never
            }
        }
        __syncthreads();
    }
    int nl = min(scanS[255], CAPL);
    for (int i = t; i < nl; i += 256)
        csr[gbase + i] = (int)stage[i];
}

// ---------- GEMM1: h1' = (x @ W1) * dinv[row], fp16-packed [N,32] __half2 ----------
__global__ __launch_bounds__(256) void k_gemm1t(const float* __restrict__ x,
                                                const float* __restrict__ W,
                                                const float* __restrict__ dinv,
                                                __half2* __restrict__ h1, int N) {
    __shared__ float xsT[DIM_IN * 64];      // [k][row] transposed tile, 32KB
    __shared__ float Ws[DIM_IN * DIM_HID];  // [k][col], 32KB
    int t = threadIdx.x;
    int row0 = blockIdx.x * 64;

#pragma unroll
    for (int i = 0; i < 8; i++)
        ((float4*)Ws)[t + 256 * i] = ((const float4*)W)[t + 256 * i];

#pragma unroll
    for (int i = 0; i < 8; i++) {
        int idx = t * 8 + i;
        int r = idx >> 5;
        int kc = idx & 31;
        int row = row0 + r;
        float4 v = (row < N) ? ((const float4*)(x + (size_t)row * DIM_IN))[kc]
                             : make_float4(0.f, 0.f, 0.f, 0.f);
        xsT[(4 * kc + 0) * 64 + r] = v.x;
        xsT[(4 * kc + 1) * 64 + r] = v.y;
        xsT[(4 * kc + 2) * 64 + r] = v.z;
        xsT[(4 * kc + 3) * 64 + r] = v.w;
    }
    __syncthreads();

    int c = t & 15;
    int r = t >> 4;
    float acc[4][4] = {};

#pragma unroll 4
    for (int k = 0; k < DIM_IN; k++) {
        float4 xa = *(const float4*)&xsT[k * 64 + 4 * r];
        float4 wb = *(const float4*)&Ws[k * DIM_HID + 4 * c];
#pragma unroll
        for (int i = 0; i < 4; i++) {
            float xi = (i == 0) ? xa.x : (i == 1) ? xa.y : (i == 2) ? xa.z : xa.w;
            acc[i][0] = fmaf(xi, wb.x, acc[i][0]);
            acc[i][1] = fmaf(xi, wb.y, acc[i][1]);
            acc[i][2] = fmaf(xi, wb.z, acc[i][2]);
            acc[i][3] = fmaf(xi, wb.w, acc[i][3]);
        }
    }

#pragma unroll
    for (int i = 0; i < 4; i++) {
        int row = row0 + 4 * r + i;
        if (row < N) {
            float d = dinv[row];
            h1[(size_t)row * 32 + 2 * c] = __floats2half2_rn(acc[i][0] * d, acc[i][1] * d);
            h1[(size_t)row * 32 + 2 * c + 1] = __floats2half2_rn(acc[i][2] * d, acc[i][3] * d);
        }
    }
}

// ---------- agg1: g = relu(di*(sum h1'[src] + h1'[node]) + b1); h2' = (g@W2)*di ----------
// Request-latency floor (~66us, R13-R15): structural for random gathers.
__global__ __launch_bounds__(256) void k_agg1(const __half2* __restrict__ h1,
                                              const int* __restrict__ csr,
                                              const int* __restrict__ offsets,
                                              const float* __restrict__ dinv,
                                              const float* __restrict__ b1,
                                              const float* __restrict__ W2,
                                              float4* __restrict__ h2, int N) {
    int t = threadIdx.x;
    int hl = t & 31;
    int node = blockIdx.x * 8 + (t >> 5);
    if (node >= N) return;

    float di = dinv[node];
    int beg = offsets[node], end = offsets[node + 1];
    __half2 a0 = h1[(size_t)node * 32 + hl];   // self-loop (pre-scaled)
    __half2 a1 = __floats2half2_rn(0.f, 0.f);

    for (int base = beg; base < end; base += 32) {
        int rem = min(32, end - base);
        int sidx = (hl < rem) ? csr[base + hl] : 0;
        if (rem == 32) {
#pragma unroll
            for (int j0 = 0; j0 < 32; j0 += 8) {
                __half2 v[8];
#pragma unroll
                for (int k = 0; k < 8; k++) {
                    int s = __shfl(sidx, j0 + k, 32);
                    v[k] = h1[(size_t)s * 32 + hl];
                }
#pragma unroll
                for (int k = 0; k < 8; k += 2) {
                    a0 = __hadd2(a0, v[k]);
                    a1 = __hadd2(a1, v[k + 1]);
                }
            }
        } else {
            int j = 0;
            for (; j + 1 < rem; j += 2) {
                int s0 = __shfl(sidx, j, 32);
                int s1 = __shfl(sidx, j + 1, 32);
                a0 = __hadd2(a0, h1[(size_t)s0 * 32 + hl]);
                a1 = __hadd2(a1, h1[(size_t)s1 * 32 + hl]);
            }
            if (j < rem) {
                int s0 = __shfl(sidx, j, 32);
                a0 = __hadd2(a0, h1[(size_t)s0 * 32 + hl]);
            }
        }
    }

    float2 f0 = __half22float2(a0);
    float2 f1 = __half22float2(a1);
    float accx = f0.x + f1.x, accy = f0.y + f1.y;

    float2 bb = ((const float2*)b1)[hl];
    float gx = fmaxf(fmaf(accx, di, bb.x), 0.f);
    float gy = fmaxf(fmaf(accy, di, bb.y), 0.f);

    const float* w0 = W2 + (2 * hl) * 3;
    const float* w1 = W2 + (2 * hl + 1) * 3;
    float v0 = gx * w0[0] + gy * w1[0];
    float v1 = gx * w0[1] + gy * w1[1];
    float v2 = gx * w0[2] + gy * w1[2];
#pragma unroll
    for (int off = 16; off > 0; off >>= 1) {
        v0 += __shfl_xor(v0, off, 64);
        v1 += __shfl_xor(v1, off, 64);
        v2 += __shfl_xor(v2, off, 64);
    }
    if (hl == 0) h2[node] = make_float4(v0 * di, v1 * di, v2 * di, 0.f);
}

// ---------- agg2: out = di*(sum h2'[src] + h2'[node]) + b2 ----------
__global__ __launch_bounds__(256) void k_agg2(const float4* __restrict__ h2,
                                              const int* __restrict__ csr,
                                              const int* __restrict__ offsets,
                                              const float* __restrict__ dinv,
                                              const float* __restrict__ b2,
                                              float* __restrict__ out, int N) {
    int t = threadIdx.x;
    int l = t & 7;
    int node = blockIdx.x * 32 + (t >> 3);
    if (node >= N) return;

    float di = dinv[node];
    int beg = offsets[node], end = offsets[node + 1];
    float a0 = 0.f, a1 = 0.f, a2 = 0.f;
    for (int e = beg + l; e < end; e += 8) {
        float4 h = h2[csr[e]];
        a0 += h.x;
        a1 += h.y;
        a2 += h.z;
    }
#pragma unroll
    for (int off = 4; off > 0; off >>= 1) {
        a0 += __shfl_xor(a0, off, 8);
        a1 += __shfl_xor(a1, off, 8);
        a2 += __shfl_xor(a2, off, 8);
    }
    if (l == 0) {
        float4 hs = h2[node];
        out[(size_t)node * 3 + 0] = fmaf(a0 + hs.x, di, b2[0]);
        out[(size_t)node * 3 + 1] = fmaf(a1 + hs.y, di, b2[1]);
        out[(size_t)node * 3 + 2] = fmaf(a2 + hs.z, di, b2[2]);
    }
}

extern "C" void kernel_launch(void* const* d_in, const int* in_sizes, int n_in,
                              void* d_out, int out_size, void* d_ws, size_t ws_size,
                              hipStream_t stream) {
    const float* x = (const float*)d_in[0];
    const int* eidx = (const int*)d_in[1];
    const float* W1 = (const float*)d_in[2];
    const float* b1 = (const float*)d_in[3];
    const float* W2 = (const float*)d_in[4];
    const float* b2 = (const float*)d_in[5];
    float* out = (float*)d_out;

    const int N = in_sizes[0] / DIM_IN;     // 100000
    const int E = in_sizes[1] / 2;          // 3200000
    const int NB = (N + BINSZ - 1) >> BSH;  // 391 bins of 256 nodes
    const int ntiles = (E + MS_TILE - 1) / MS_TILE;  // 782

    char* w = (char*)d_ws;
    size_t off = 0;
    auto carve = [&](size_t bytes) -> char* {
        char* p = w + off;
        off += (bytes + 255) & ~(size_t)255;
        return p;
    };
    int* offsets = (int*)carve((size_t)(N + 1) * 4);
    float* dinv = (float*)carve((size_t)N * 4);
    int* csr = (int*)carve((size_t)E * 4);
    int* offs = (int*)carve((size_t)ntiles * (NB + 1) * 4);  // per-tile scan table
    int* binTot = (int*)carve(MAXNB * 4);
    int* binBase = (int*)carve(MAXNB * 4);
    float4* h2 = (float4*)carve((size_t)N * 16);

    // uni region: tile-sorted packed words (msplit..fillA2), then fp16 h1'.
    size_t h1_bytes = (size_t)N * DIM_HID * 2;
    size_t sorted_bytes = (size_t)E * 4;
    size_t uni_bytes = sorted_bytes > h1_bytes ? sorted_bytes : h1_bytes;
    char* uni = carve(uni_bytes);
    unsigned int* sorted = (unsigned int*)uni;
    __half2* h1 = (__half2*)uni;        // aliased: valid only after k_fillA2

    k_msplit4<<<ntiles, 256, 0, stream>>>(eidx, sorted, offs, E, NB);
    k_binsum<<<NB, 256, 0, stream>>>(offs, binTot, ntiles, NB);
    k_binscan<<<1, 512, 0, stream>>>(binTot, binBase, NB);
    k_fillA2<<<NB, 256, 0, stream>>>(sorted, offs, binBase, offsets, dinv, csr,
                                     ntiles, NB, N);

    k_gemm1t<<<(N + 63) / 64, 256, 0, stream>>>(x, W1, dinv, h1, N);
    k_agg1<<<(N + 7) / 8, 256, 0, stream>>>(h1, csr, offsets, dinv, b1, W2, h2, N);
    k_agg2<<<(N + 31) / 32, 256, 0, stream>>>(h2, csr, offsets, dinv, b2, out, N);
}

// Round 17
// 183.839 us; speedup vs baseline: 1.1866x; 1.1866x over previous
//
#include <hip/hip_runtime.h>
#include <hip/hip_fp16.h>
#include <cstdint>
#include <cstddef>

#define DIM_IN 128
#define DIM_HID 64
#define MS_TILE 8192      // edges per multisplit tile; runs = MS_TILE/NB ~ 42 edges
#define OVF_CAP 32768     // overflow valve capacity (edges)
#define BSH 9             // bin shift: 512-node bins (R17: longer runs, less write amp)
#define BINSZ 512
#define MAXNB 512
#define CAPL 20480        // LDS stage (80KB); bin mean 16327, ~32 sigma headroom

// native clang vectors (nontemporal builtins reject HIP_vector_type classes)
typedef int v2i __attribute__((ext_vector_type(2)));

// ---------- multisplit, 2-pass: hist+reserve, then re-read & place ----------
// R16 post-mortem: tile-major sort made the consumer slow; reverted. R17 cuts
// msplit's HBM-writeback (the real cost: 50-62MB on 12.8MB payload) by halving
// bin count -> ~42-edge runs (~168B) -> amp ~1.5.
__global__ __launch_bounds__(512) void k_msplit3(const int* __restrict__ eidx,
                                                 int* __restrict__ binCursor,
                                                 unsigned int* __restrict__ binned,
                                                 int* __restrict__ ovfCnt,
                                                 v2i* __restrict__ ovf,
                                                 int E, int NB, int cap) {
    __shared__ int hist[256], base[256];
    __shared__ int stF;
    int t = threadIdx.x;
    if (t == 0) {           // int32 vs int64 detect (odd words of first 64 i64 all 0)
        int o = 0;
        for (int j = 1; j < 128; j += 2) o |= eidx[j];
        stF = (o == 0) ? 2 : 1;
    }
    __syncthreads();
    int st = stF;
    int ntiles = (E + MS_TILE - 1) / MS_TILE;

    for (int tile = blockIdx.x; tile < ntiles; tile += gridDim.x) {
        int e0 = tile * MS_TILE;
        int e1 = min(e0 + MS_TILE, E);

        if (t < 256) hist[t] = 0;
        __syncthreads();
        for (int e = e0 + t; e < e1; e += 512) {
            int d = (st == 2) ? ((const v2i*)eidx)[E + e].x : eidx[E + e];
            atomicAdd(&hist[d >> BSH], 1);
        }
        __syncthreads();
        if (t < NB && hist[t] > 0) base[t] = atomicAdd(&binCursor[t], hist[t]);
        __syncthreads();
        if (t < 256) hist[t] = 0;   // reuse as rank counters
        __syncthreads();
        for (int e = e0 + t; e < e1; e += 512) {
            int s, d;
            if (st == 2) {
                s = ((const v2i*)eidx)[e].x;
                d = ((const v2i*)eidx)[E + e].x;
            } else {
                s = eidx[e];
                d = eidx[E + e];
            }
            int b = d >> BSH;
            int r = atomicAdd(&hist[b], 1);
            int local = base[b] + r;
            if (local < cap) {
                binned[(size_t)b * cap + local] =
                    ((unsigned int)s << BSH) | (unsigned int)(d & (BINSZ - 1));
            } else {
                int o = atomicAdd(ovfCnt, 1);
                if (o < OVF_CAP) ovf[o] = (v2i){s, d};
            }
        }
        __syncthreads();
    }
}

// ---------- exclusive scan of bin totals -> binBase ----------
__global__ __launch_bounds__(512) void k_binscan(const int* __restrict__ binCursor,
                                                 int* __restrict__ binBase,
                                                 int NB, int cap) {
    __shared__ int sh[512];
    int t = threadIdx.x;
    int v = (t < NB) ? min(binCursor[t], cap) : 0;
    sh[t] = v;
    __syncthreads();
    for (int d = 1; d < 512; d <<= 1) {
        int add = (t >= d) ? sh[t - d] : 0;
        __syncthreads();
        sh[t] += add;
        __syncthreads();
    }
    if (t < NB) binBase[t] = sh[t] - v;
}

// ---------- fused fill: hist + scan -> offsets/dinv/cursor; stage + flush csr ----------
// 512 threads / 512-node bins / 80KB stage (R17).
__global__ __launch_bounds__(512) void k_fillA(const unsigned int* __restrict__ binned,
                                               const int* __restrict__ binCursor,
                                               const int* __restrict__ binBase,
                                               int* __restrict__ offsets,
                                               int* __restrict__ cursor,
                                               float* __restrict__ dinv,
                                               int* __restrict__ csr,
                                               int cap, int N) {
    __shared__ int hist[BINSZ], scanS[BINSZ], curL[BINSZ];
    __shared__ unsigned int stage[CAPL];
    int b = blockIdx.x;
    int t = threadIdx.x;
    int g0 = b << BSH;
    int g = g0 + t;
    int n = min(binCursor[b], cap);
    const unsigned int* p = binned + (size_t)b * cap;

    hist[t] = 0;
    __syncthreads();
    for (int i = t; i < n; i += 512)
        atomicAdd(&hist[p[i] & (BINSZ - 1)], 1);
    __syncthreads();
    int h = hist[t];
    scanS[t] = h;
    __syncthreads();
    for (int d = 1; d < 512; d <<= 1) {
        int add = (t >= d) ? scanS[t - d] : 0;
        __syncthreads();
        scanS[t] += add;
        __syncthreads();
    }
    int excl = scanS[t] - h;
    int gbase = binBase[b];
    if (g < N) {
        offsets[g] = gbase + excl;
        dinv[g] = rsqrtf((float)(h + 1));
    }
    if (t == 511) offsets[min(g0 + BINSZ, N)] = gbase + scanS[511];  // race-benign dup

    curL[t] = excl;
    __syncthreads();
    int nl = min(n, CAPL);
    for (int i = t; i < nl; i += 512) {
        unsigned int w = p[i];
        int pos = atomicAdd(&curL[w & (BINSZ - 1)], 1);
        if (pos < CAPL) stage[pos] = w >> BSH;
    }
    __syncthreads();
    if (g < N) cursor[g] = gbase + curL[t];     // final positions (ovf valve)
    for (int i = t; i < nl; i += 512)
        csr[gbase + i] = (int)stage[i];         // coalesced flush
    __syncthreads();
    for (int i = CAPL + t; i < n; i += 512) {   // dead by construction
        unsigned int w = p[i];
        int pos = atomicAdd(&cursor[g0 + (int)(w & (BINSZ - 1))], 1);
        csr[pos] = (int)(w >> BSH);
    }
}

// ---------- drain overflow valve (normally 0 edges) ----------
__global__ void k_ovf(const int* __restrict__ ovfCnt, const v2i* __restrict__ ovf,
                      int* __restrict__ cursor, int* __restrict__ csr) {
    int n = min(*ovfCnt, OVF_CAP);
    for (int i = threadIdx.x; i < n; i += 256) {
        v2i e = ovf[i];
        int pos = atomicAdd(&cursor[e.y], 1);
        csr[pos] = e.x;
    }
}

// ---------- GEMM1: h1' = (x @ W1) * dinv[row], fp16-packed [N,32] __half2 ----------
__global__ __launch_bounds__(256) void k_gemm1t(const float* __restrict__ x,
                                                const float* __restrict__ W,
                                                const float* __restrict__ dinv,
                                                __half2* __restrict__ h1, int N) {
    __shared__ float xsT[DIM_IN * 64];      // [k][row] transposed tile, 32KB
    __shared__ float Ws[DIM_IN * DIM_HID];  // [k][col], 32KB
    int t = threadIdx.x;
    int row0 = blockIdx.x * 64;

#pragma unroll
    for (int i = 0; i < 8; i++)
        ((float4*)Ws)[t + 256 * i] = ((const float4*)W)[t + 256 * i];

#pragma unroll
    for (int i = 0; i < 8; i++) {
        int idx = t * 8 + i;
        int r = idx >> 5;
        int kc = idx & 31;
        int row = row0 + r;
        float4 v = (row < N) ? ((const float4*)(x + (size_t)row * DIM_IN))[kc]
                             : make_float4(0.f, 0.f, 0.f, 0.f);
        xsT[(4 * kc + 0) * 64 + r] = v.x;
        xsT[(4 * kc + 1) * 64 + r] = v.y;
        xsT[(4 * kc + 2) * 64 + r] = v.z;
        xsT[(4 * kc + 3) * 64 + r] = v.w;
    }
    __syncthreads();

    int c = t & 15;
    int r = t >> 4;
    float acc[4][4] = {};

#pragma unroll 4
    for (int k = 0; k < DIM_IN; k++) {
        float4 xa = *(const float4*)&xsT[k * 64 + 4 * r];
        float4 wb = *(const float4*)&Ws[k * DIM_HID + 4 * c];
#pragma unroll
        for (int i = 0; i < 4; i++) {
            float xi = (i == 0) ? xa.x : (i == 1) ? xa.y : (i == 2) ? xa.z : xa.w;
            acc[i][0] = fmaf(xi, wb.x, acc[i][0]);
            acc[i][1] = fmaf(xi, wb.y, acc[i][1]);
            acc[i][2] = fmaf(xi, wb.z, acc[i][2]);
            acc[i][3] = fmaf(xi, wb.w, acc[i][3]);
        }
    }

#pragma unroll
    for (int i = 0; i < 4; i++) {
        int row = row0 + 4 * r + i;
        if (row < N) {
            float d = dinv[row];
            h1[(size_t)row * 32 + 2 * c] = __floats2half2_rn(acc[i][0] * d, acc[i][1] * d);
            h1[(size_t)row * 32 + 2 * c + 1] = __floats2half2_rn(acc[i][2] * d, acc[i][3] * d);
        }
    }
}

// ---------- agg1: g = relu(di*(sum h1'[src] + h1'[node]) + b1); h2' = (g@W2)*di ----------
// Request-latency floor (~66us, R13-R16): structural for random gathers.
__global__ __launch_bounds__(256) void k_agg1(const __half2* __restrict__ h1,
                                              const int* __restrict__ csr,
                                              const int* __restrict__ offsets,
                                              const float* __restrict__ dinv,
                                              const float* __restrict__ b1,
                                              const float* __restrict__ W2,
                                              float4* __restrict__ h2, int N) {
    int t = threadIdx.x;
    int hl = t & 31;
    int node = blockIdx.x * 8 + (t >> 5);
    if (node >= N) return;

    float di = dinv[node];
    int beg = offsets[node], end = offsets[node + 1];
    __half2 a0 = h1[(size_t)node * 32 + hl];   // self-loop (pre-scaled)
    __half2 a1 = __floats2half2_rn(0.f, 0.f);

    for (int base = beg; base < end; base += 32) {
        int rem = min(32, end - base);
        int sidx = (hl < rem) ? csr[base + hl] : 0;
        if (rem == 32) {
#pragma unroll
            for (int j0 = 0; j0 < 32; j0 += 8) {
                __half2 v[8];
#pragma unroll
                for (int k = 0; k < 8; k++) {
                    int s = __shfl(sidx, j0 + k, 32);
                    v[k] = h1[(size_t)s * 32 + hl];
                }
#pragma unroll
                for (int k = 0; k < 8; k += 2) {
                    a0 = __hadd2(a0, v[k]);
                    a1 = __hadd2(a1, v[k + 1]);
                }
            }
        } else {
            int j = 0;
            for (; j + 1 < rem; j += 2) {
                int s0 = __shfl(sidx, j, 32);
                int s1 = __shfl(sidx, j + 1, 32);
                a0 = __hadd2(a0, h1[(size_t)s0 * 32 + hl]);
                a1 = __hadd2(a1, h1[(size_t)s1 * 32 + hl]);
            }
            if (j < rem) {
                int s0 = __shfl(sidx, j, 32);
                a0 = __hadd2(a0, h1[(size_t)s0 * 32 + hl]);
            }
        }
    }

    float2 f0 = __half22float2(a0);
    float2 f1 = __half22float2(a1);
    float accx = f0.x + f1.x, accy = f0.y + f1.y;

    float2 bb = ((const float2*)b1)[hl];
    float gx = fmaxf(fmaf(accx, di, bb.x), 0.f);
    float gy = fmaxf(fmaf(accy, di, bb.y), 0.f);

    const float* w0 = W2 + (2 * hl) * 3;
    const float* w1 = W2 + (2 * hl + 1) * 3;
    float v0 = gx * w0[0] + gy * w1[0];
    float v1 = gx * w0[1] + gy * w1[1];
    float v2 = gx * w0[2] + gy * w1[2];
#pragma unroll
    for (int off = 16; off > 0; off >>= 1) {
        v0 += __shfl_xor(v0, off, 64);
        v1 += __shfl_xor(v1, off, 64);
        v2 += __shfl_xor(v2, off, 64);
    }
    if (hl == 0) h2[node] = make_float4(v0 * di, v1 * di, v2 * di, 0.f);
}

// ---------- agg2: out = di*(sum h2'[src] + h2'[node]) + b2 ----------
__global__ __launch_bounds__(256) void k_agg2(const float4* __restrict__ h2,
                                              const int* __restrict__ csr,
                                              const int* __restrict__ offsets,
                                              const float* __restrict__ dinv,
                                              const float* __restrict__ b2,
                                              float* __restrict__ out, int N) {
    int t = threadIdx.x;
    int l = t & 7;
    int node = blockIdx.x * 32 + (t >> 3);
    if (node >= N) return;

    float di = dinv[node];
    int beg = offsets[node], end = offsets[node + 1];
    float a0 = 0.f, a1 = 0.f, a2 = 0.f;
    for (int e = beg + l; e < end; e += 8) {
        float4 h = h2[csr[e]];
        a0 += h.x;
        a1 += h.y;
        a2 += h.z;
    }
#pragma unroll
    for (int off = 4; off > 0; off >>= 1) {
        a0 += __shfl_xor(a0, off, 8);
        a1 += __shfl_xor(a1, off, 8);
        a2 += __shfl_xor(a2, off, 8);
    }
    if (l == 0) {
        float4 hs = h2[node];
        out[(size_t)node * 3 + 0] = fmaf(a0 + hs.x, di, b2[0]);
        out[(size_t)node * 3 + 1] = fmaf(a1 + hs.y, di, b2[1]);
        out[(size_t)node * 3 + 2] = fmaf(a2 + hs.z, di, b2[2]);
    }
}

extern "C" void kernel_launch(void* const* d_in, const int* in_sizes, int n_in,
                              void* d_out, int out_size, void* d_ws, size_t ws_size,
                              hipStream_t stream) {
    const float* x = (const float*)d_in[0];
    const int* eidx = (const int*)d_in[1];
    const float* W1 = (const float*)d_in[2];
    const float* b1 = (const float*)d_in[3];
    const float* W2 = (const float*)d_in[4];
    const float* b2 = (const float*)d_in[5];
    float* out = (float*)d_out;

    const int N = in_sizes[0] / DIM_IN;     // 100000
    const int E = in_sizes[1] / 2;          // 3200000
    const int NB = (N + BINSZ - 1) >> BSH;  // 196 bins of 512 nodes

    char* w = (char*)d_ws;
    size_t off = 0;
    auto carve = [&](size_t bytes) -> char* {
        char* p = w + off;
        off += (bytes + 255) & ~(size_t)255;
        return p;
    };
    int* offsets = (int*)carve((size_t)(N + 1) * 4);
    int* cursor = (int*)carve((size_t)N * 4);
    float* dinv = (float*)carve((size_t)N * 4);
    int* csr = (int*)carve((size_t)E * 4);
    int* binCursor = (int*)carve(MAXNB * 4);
    int* ovfCnt = (int*)carve(16);
    v2i* ovf = (v2i*)carve((size_t)OVF_CAP * 8);
    int* binBase = (int*)carve(MAXNB * 4);
    float4* h2 = (float4*)carve((size_t)N * 16);

    // uni region: packed binned words (msplit..fillA), then aliased by fp16 h1'.
    size_t h1_bytes = (size_t)N * DIM_HID * 2;
    int capDes = E / NB + E / NB / 16 + 256;     // mean + margin; < CAPL by construction
    size_t binned_des = (size_t)NB * capDes * 4;
    size_t uni_avail = (ws_size > off + 256) ? (ws_size - off - 256) : h1_bytes;
    size_t uni_bytes = binned_des > h1_bytes ? binned_des : h1_bytes;
    if (uni_bytes > uni_avail) uni_bytes = uni_avail > h1_bytes ? uni_avail : h1_bytes;
    char* uni = carve(uni_bytes);
    unsigned int* binned = (unsigned int*)uni;
    __half2* h1 = (__half2*)uni;        // aliased: valid only after k_fillA
    int cap = (int)(uni_bytes / ((size_t)NB * 4));
    if (cap > capDes) cap = capDes;
    if (cap > CAPL) cap = CAPL;         // keep the fillA stage invariant

    (void)hipMemsetAsync(binCursor, 0, MAXNB * 4 + 256, stream);  // binCursor + ovfCnt

    int ntiles = (E + MS_TILE - 1) / MS_TILE;
    k_msplit3<<<ntiles, 512, 0, stream>>>(eidx, binCursor, binned, ovfCnt, ovf,
                                          E, NB, cap);
    k_binscan<<<1, 512, 0, stream>>>(binCursor, binBase, NB, cap);
    k_fillA<<<NB, 512, 0, stream>>>(binned, binCursor, binBase, offsets, cursor,
                                    dinv, csr, cap, N);
    k_ovf<<<1, 256, 0, stream>>>(ovfCnt, ovf, cursor, csr);

    k_gemm1t<<<(N + 63) / 64, 256, 0, stream>>>(x, W1, dinv, h1, N);
    k_agg1<<<(N + 7) / 8, 256, 0, stream>>>(h1, csr, offsets, dinv, b1, W2, h2, N);
    k_agg2<<<(N + 31) / 32, 256, 0, stream>>>(h2, csr, offsets, dinv, b2, out, N);
}

// Round 18
// 181.072 us; speedup vs baseline: 1.2047x; 1.0153x over previous
//
#include <hip/hip_runtime.h>
#include <hip/hip_fp16.h>
#include <cstdint>
#include <cstddef>

#define DIM_IN 128
#define DIM_HID 64
#define MS_TILE 16384     // edges per multisplit tile; runs = MS_TILE/NB ~ 84 edges
#define OVF_CAP 32768     // overflow valve capacity (edges)
#define BSH 9             // bin shift: 512-node bins
#define BINSZ 512
#define MAXNB 512
#define CAPL 20480        // LDS stage (80KB); bin mean 16327, ~32 sigma headroom

// native clang vectors (nontemporal builtins reject HIP_vector_type classes)
typedef int v2i __attribute__((ext_vector_type(2)));

// ---------- multisplit, 2-pass: hist+reserve, then re-read & place ----------
// R18: MS_TILE 16384 + 1024 threads (occupancy-neutral vs R17: 196WGx16w ~ 12
// waves/CU) -> ~84-edge runs (~336B) -> write amp ~1.2 (R15 measured 61.7MB
// scattered-write cost; R17's 512-bins was the same lever, halving again).
__global__ __launch_bounds__(1024) void k_msplit3(const int* __restrict__ eidx,
                                                  int* __restrict__ binCursor,
                                                  unsigned int* __restrict__ binned,
                                                  int* __restrict__ ovfCnt,
                                                  v2i* __restrict__ ovf,
                                                  int E, int NB, int cap) {
    __shared__ int hist[256], base[256];
    __shared__ int stF;
    int t = threadIdx.x;
    if (t == 0) {           // int32 vs int64 detect (odd words of first 64 i64 all 0)
        int o = 0;
        for (int j = 1; j < 128; j += 2) o |= eidx[j];
        stF = (o == 0) ? 2 : 1;
    }
    __syncthreads();
    int st = stF;
    int ntiles = (E + MS_TILE - 1) / MS_TILE;

    for (int tile = blockIdx.x; tile < ntiles; tile += gridDim.x) {
        int e0 = tile * MS_TILE;
        int e1 = min(e0 + MS_TILE, E);

        if (t < 256) hist[t] = 0;
        __syncthreads();
        for (int e = e0 + t; e < e1; e += 1024) {
            int d = (st == 2) ? ((const v2i*)eidx)[E + e].x : eidx[E + e];
            atomicAdd(&hist[d >> BSH], 1);
        }
        __syncthreads();
        if (t < NB && hist[t] > 0) base[t] = atomicAdd(&binCursor[t], hist[t]);
        __syncthreads();
        if (t < 256) hist[t] = 0;   // reuse as rank counters
        __syncthreads();
        for (int e = e0 + t; e < e1; e += 1024) {
            int s, d;
            if (st == 2) {
                s = ((const v2i*)eidx)[e].x;
                d = ((const v2i*)eidx)[E + e].x;
            } else {
                s = eidx[e];
                d = eidx[E + e];
            }
            int b = d >> BSH;
            int r = atomicAdd(&hist[b], 1);
            int local = base[b] + r;
            if (local < cap) {
                binned[(size_t)b * cap + local] =
                    ((unsigned int)s << BSH) | (unsigned int)(d & (BINSZ - 1));
            } else {
                int o = atomicAdd(ovfCnt, 1);
                if (o < OVF_CAP) ovf[o] = (v2i){s, d};
            }
        }
        __syncthreads();
    }
}

// ---------- exclusive scan of bin totals -> binBase ----------
__global__ __launch_bounds__(512) void k_binscan(const int* __restrict__ binCursor,
                                                 int* __restrict__ binBase,
                                                 int NB, int cap) {
    __shared__ int sh[512];
    int t = threadIdx.x;
    int v = (t < NB) ? min(binCursor[t], cap) : 0;
    sh[t] = v;
    __syncthreads();
    for (int d = 1; d < 512; d <<= 1) {
        int add = (t >= d) ? sh[t - d] : 0;
        __syncthreads();
        sh[t] += add;
        __syncthreads();
    }
    if (t < NB) binBase[t] = sh[t] - v;
}

// ---------- fused fill: hist + scan -> offsets/dinv/cursor; stage + flush csr ----------
__global__ __launch_bounds__(512) void k_fillA(const unsigned int* __restrict__ binned,
                                               const int* __restrict__ binCursor,
                                               const int* __restrict__ binBase,
                                               int* __restrict__ offsets,
                                               int* __restrict__ cursor,
                                               float* __restrict__ dinv,
                                               int* __restrict__ csr,
                                               int cap, int N) {
    __shared__ int hist[BINSZ], scanS[BINSZ], curL[BINSZ];
    __shared__ unsigned int stage[CAPL];
    int b = blockIdx.x;
    int t = threadIdx.x;
    int g0 = b << BSH;
    int g = g0 + t;
    int n = min(binCursor[b], cap);
    const unsigned int* p = binned + (size_t)b * cap;

    hist[t] = 0;
    __syncthreads();
    for (int i = t; i < n; i += 512)
        atomicAdd(&hist[p[i] & (BINSZ - 1)], 1);
    __syncthreads();
    int h = hist[t];
    scanS[t] = h;
    __syncthreads();
    for (int d = 1; d < 512; d <<= 1) {
        int add = (t >= d) ? scanS[t - d] : 0;
        __syncthreads();
        scanS[t] += add;
        __syncthreads();
    }
    int excl = scanS[t] - h;
    int gbase = binBase[b];
    if (g < N) {
        offsets[g] = gbase + excl;
        dinv[g] = rsqrtf((float)(h + 1));
    }
    if (t == 511) offsets[min(g0 + BINSZ, N)] = gbase + scanS[511];  // race-benign dup

    curL[t] = excl;
    __syncthreads();
    int nl = min(n, CAPL);
    for (int i = t; i < nl; i += 512) {
        unsigned int w = p[i];
        int pos = atomicAdd(&curL[w & (BINSZ - 1)], 1);
        if (pos < CAPL) stage[pos] = w >> BSH;
    }
    __syncthreads();
    if (g < N) cursor[g] = gbase + curL[t];     // final positions (ovf valve)
    for (int i = t; i < nl; i += 512)
        csr[gbase + i] = (int)stage[i];         // coalesced flush
    __syncthreads();
    for (int i = CAPL + t; i < n; i += 512) {   // dead by construction
        unsigned int w = p[i];
        int pos = atomicAdd(&cursor[g0 + (int)(w & (BINSZ - 1))], 1);
        csr[pos] = (int)(w >> BSH);
    }
}

// ---------- drain overflow valve (normally 0 edges) ----------
__global__ void k_ovf(const int* __restrict__ ovfCnt, const v2i* __restrict__ ovf,
                      int* __restrict__ cursor, int* __restrict__ csr) {
    int n = min(*ovfCnt, OVF_CAP);
    for (int i = threadIdx.x; i < n; i += 256) {
        v2i e = ovf[i];
        int pos = atomicAdd(&cursor[e.y], 1);
        csr[pos] = e.x;
    }
}

// ---------- GEMM1: h1' = (x @ W1) * dinv[row], fp16-packed [N,32] __half2 ----------
// R18: x-tile staged fp16 -> block LDS 64->48KB -> 3 blocks/CU (+50% waves;
// R7 post-mortem showed this kernel is LDS-latency bound at 2 waves/SIMD).
__global__ __launch_bounds__(256) void k_gemm1t(const float* __restrict__ x,
                                                const float* __restrict__ W,
                                                const float* __restrict__ dinv,
                                                __half2* __restrict__ h1, int N) {
    __shared__ __half xsT[DIM_IN * 64];     // [k][row] transposed tile, 16KB fp16
    __shared__ float Ws[DIM_IN * DIM_HID];  // [k][col], 32KB
    int t = threadIdx.x;
    int row0 = blockIdx.x * 64;

#pragma unroll
    for (int i = 0; i < 8; i++)
        ((float4*)Ws)[t + 256 * i] = ((const float4*)W)[t + 256 * i];

#pragma unroll
    for (int i = 0; i < 8; i++) {
        int idx = t * 8 + i;
        int r = idx >> 5;
        int kc = idx & 31;
        int row = row0 + r;
        float4 v = (row < N) ? ((const float4*)(x + (size_t)row * DIM_IN))[kc]
                             : make_float4(0.f, 0.f, 0.f, 0.f);
        xsT[(4 * kc + 0) * 64 + r] = __float2half(v.x);
        xsT[(4 * kc + 1) * 64 + r] = __float2half(v.y);
        xsT[(4 * kc + 2) * 64 + r] = __float2half(v.z);
        xsT[(4 * kc + 3) * 64 + r] = __float2half(v.w);
    }
    __syncthreads();

    int c = t & 15;
    int r = t >> 4;
    float acc[4][4] = {};

#pragma unroll 4
    for (int k = 0; k < DIM_IN; k++) {
        __half2 xh01 = *(const __half2*)&xsT[k * 64 + 4 * r];
        __half2 xh23 = *(const __half2*)&xsT[k * 64 + 4 * r + 2];
        float2 x01 = __half22float2(xh01);
        float2 x23 = __half22float2(xh23);
        float4 wb = *(const float4*)&Ws[k * DIM_HID + 4 * c];
        float xi[4] = {x01.x, x01.y, x23.x, x23.y};
#pragma unroll
        for (int i = 0; i < 4; i++) {
            acc[i][0] = fmaf(xi[i], wb.x, acc[i][0]);
            acc[i][1] = fmaf(xi[i], wb.y, acc[i][1]);
            acc[i][2] = fmaf(xi[i], wb.z, acc[i][2]);
            acc[i][3] = fmaf(xi[i], wb.w, acc[i][3]);
        }
    }

#pragma unroll
    for (int i = 0; i < 4; i++) {
        int row = row0 + 4 * r + i;
        if (row < N) {
            float d = dinv[row];
            h1[(size_t)row * 32 + 2 * c] = __floats2half2_rn(acc[i][0] * d, acc[i][1] * d);
            h1[(size_t)row * 32 + 2 * c + 1] = __floats2half2_rn(acc[i][2] * d, acc[i][3] * d);
        }
    }
}

// ---------- agg1: g = relu(di*(sum h1'[src] + h1'[node]) + b1); h2' = (g@W2)*di ----------
// Request-latency floor (~66us, R13-R17): structural for random 128B gathers.
__global__ __launch_bounds__(256) void k_agg1(const __half2* __restrict__ h1,
                                              const int* __restrict__ csr,
                                              const int* __restrict__ offsets,
                                              const float* __restrict__ dinv,
                                              const float* __restrict__ b1,
                                              const float* __restrict__ W2,
                                              float4* __restrict__ h2, int N) {
    int t = threadIdx.x;
    int hl = t & 31;
    int node = blockIdx.x * 8 + (t >> 5);
    if (node >= N) return;

    float di = dinv[node];
    int beg = offsets[node], end = offsets[node + 1];
    __half2 a0 = h1[(size_t)node * 32 + hl];   // self-loop (pre-scaled)
    __half2 a1 = __floats2half2_rn(0.f, 0.f);

    for (int base = beg; base < end; base += 32) {
        int rem = min(32, end - base);
        int sidx = (hl < rem) ? csr[base + hl] : 0;
        if (rem == 32) {
#pragma unroll
            for (int j0 = 0; j0 < 32; j0 += 8) {
                __half2 v[8];
#pragma unroll
                for (int k = 0; k < 8; k++) {
                    int s = __shfl(sidx, j0 + k, 32);
                    v[k] = h1[(size_t)s * 32 + hl];
                }
#pragma unroll
                for (int k = 0; k < 8; k += 2) {
                    a0 = __hadd2(a0, v[k]);
                    a1 = __hadd2(a1, v[k + 1]);
                }
            }
        } else {
            int j = 0;
            for (; j + 1 < rem; j += 2) {
                int s0 = __shfl(sidx, j, 32);
                int s1 = __shfl(sidx, j + 1, 32);
                a0 = __hadd2(a0, h1[(size_t)s0 * 32 + hl]);
                a1 = __hadd2(a1, h1[(size_t)s1 * 32 + hl]);
            }
            if (j < rem) {
                int s0 = __shfl(sidx, j, 32);
                a0 = __hadd2(a0, h1[(size_t)s0 * 32 + hl]);
            }
        }
    }

    float2 f0 = __half22float2(a0);
    float2 f1 = __half22float2(a1);
    float accx = f0.x + f1.x, accy = f0.y + f1.y;

    float2 bb = ((const float2*)b1)[hl];
    float gx = fmaxf(fmaf(accx, di, bb.x), 0.f);
    float gy = fmaxf(fmaf(accy, di, bb.y), 0.f);

    const float* w0 = W2 + (2 * hl) * 3;
    const float* w1 = W2 + (2 * hl + 1) * 3;
    float v0 = gx * w0[0] + gy * w1[0];
    float v1 = gx * w0[1] + gy * w1[1];
    float v2 = gx * w0[2] + gy * w1[2];
#pragma unroll
    for (int off = 16; off > 0; off >>= 1) {
        v0 += __shfl_xor(v0, off, 64);
        v1 += __shfl_xor(v1, off, 64);
        v2 += __shfl_xor(v2, off, 64);
    }
    if (hl == 0) h2[node] = make_float4(v0 * di, v1 * di, v2 * di, 0.f);
}

// ---------- agg2: out = di*(sum h2'[src] + h2'[node]) + b2 ----------
__global__ __launch_bounds__(256) void k_agg2(const float4* __restrict__ h2,
                                              const int* __restrict__ csr,
                                              const int* __restrict__ offsets,
                                              const float* __restrict__ dinv,
                                              const float* __restrict__ b2,
                                              float* __restrict__ out, int N) {
    int t = threadIdx.x;
    int l = t & 7;
    int node = blockIdx.x * 32 + (t >> 3);
    if (node >= N) return;

    float di = dinv[node];
    int beg = offsets[node], end = offsets[node + 1];
    float a0 = 0.f, a1 = 0.f, a2 = 0.f;
    for (int e = beg + l; e < end; e += 8) {
        float4 h = h2[csr[e]];
        a0 += h.x;
        a1 += h.y;
        a2 += h.z;
    }
#pragma unroll
    for (int off = 4; off > 0; off >>= 1) {
        a0 += __shfl_xor(a0, off, 8);
        a1 += __shfl_xor(a1, off, 8);
        a2 += __shfl_xor(a2, off, 8);
    }
    if (l == 0) {
        float4 hs = h2[node];
        out[(size_t)node * 3 + 0] = fmaf(a0 + hs.x, di, b2[0]);
        out[(size_t)node * 3 + 1] = fmaf(a1 + hs.y, di, b2[1]);
        out[(size_t)node * 3 + 2] = fmaf(a2 + hs.z, di, b2[2]);
    }
}

extern "C" void kernel_launch(void* const* d_in, const int* in_sizes, int n_in,
                              void* d_out, int out_size, void* d_ws, size_t ws_size,
                              hipStream_t stream) {
    const float* x = (const float*)d_in[0];
    const int* eidx = (const int*)d_in[1];
    const float* W1 = (const float*)d_in[2];
    const float* b1 = (const float*)d_in[3];
    const float* W2 = (const float*)d_in[4];
    const float* b2 = (const float*)d_in[5];
    float* out = (float*)d_out;

    const int N = in_sizes[0] / DIM_IN;     // 100000
    const int E = in_sizes[1] / 2;          // 3200000
    const int NB = (N + BINSZ - 1) >> BSH;  // 196 bins of 512 nodes

    char* w = (char*)d_ws;
    size_t off = 0;
    auto carve = [&](size_t bytes) -> char* {
        char* p = w + off;
        off += (bytes + 255) & ~(size_t)255;
        return p;
    };
    int* offsets = (int*)carve((size_t)(N + 1) * 4);
    int* cursor = (int*)carve((size_t)N * 4);
    float* dinv = (float*)carve((size_t)N * 4);
    int* csr = (int*)carve((size_t)E * 4);
    int* binCursor = (int*)carve(MAXNB * 4);
    int* ovfCnt = (int*)carve(16);
    v2i* ovf = (v2i*)carve((size_t)OVF_CAP * 8);
    int* binBase = (int*)carve(MAXNB * 4);
    float4* h2 = (float4*)carve((size_t)N * 16);

    // uni region: packed binned words (msplit..fillA), then aliased by fp16 h1'.
    size_t h1_bytes = (size_t)N * DIM_HID * 2;
    int capDes = E / NB + E / NB / 16 + 256;     // mean + margin; < CAPL by construction
    size_t binned_des = (size_t)NB * capDes * 4;
    size_t uni_avail = (ws_size > off + 256) ? (ws_size - off - 256) : h1_bytes;
    size_t uni_bytes = binned_des > h1_bytes ? binned_des : h1_bytes;
    if (uni_bytes > uni_avail) uni_bytes = uni_avail > h1_bytes ? uni_avail : h1_bytes;
    char* uni = carve(uni_bytes);
    unsigned int* binned = (unsigned int*)uni;
    __half2* h1 = (__half2*)uni;        // aliased: valid only after k_fillA
    int cap = (int)(uni_bytes / ((size_t)NB * 4));
    if (cap > capDes) cap = capDes;
    if (cap > CAPL) cap = CAPL;         // keep the fillA stage invariant

    (void)hipMemsetAsync(binCursor, 0, MAXNB * 4 + 256, stream);  // binCursor + ovfCnt

    int ntiles = (E + MS_TILE - 1) / MS_TILE;
    k_msplit3<<<ntiles, 1024, 0, stream>>>(eidx, binCursor, binned, ovfCnt, ovf,
                                           E, NB, cap);
    k_binscan<<<1, 512, 0, stream>>>(binCursor, binBase, NB, cap);
    k_fillA<<<NB, 512, 0, stream>>>(binned, binCursor, binBase, offsets, cursor,
                                    dinv, csr, cap, N);
    k_ovf<<<1, 256, 0, stream>>>(ovfCnt, ovf, cursor, csr);

    k_gemm1t<<<(N + 63) / 64, 256, 0, stream>>>(x, W1, dinv, h1, N);
    k_agg1<<<(N + 7) / 8, 256, 0, stream>>>(h1, csr, offsets, dinv, b1, W2, h2, N);
    k_agg2<<<(N + 31) / 32, 256, 0, stream>>>(h2, csr, offsets, dinv, b2, out, N);
}

// Round 19
// 174.801 us; speedup vs baseline: 1.2479x; 1.0359x over previous
//
#include <hip/hip_runtime.h>
#include <hip/hip_fp16.h>
#include <cstdint>
#include <cstddef>

#define DIM_IN 128
#define DIM_HID 64
#define MS_TILE 16384     // edges per multisplit tile; runs = MS_TILE/NB ~ 84 edges
#define OVF_CAP 32768     // overflow valve capacity (edges)
#define BSH 9             // bin shift: 512-node bins
#define BINSZ 512
#define MAXNB 512
#define CAPL 20480        // LDS stage (80KB); bin mean 16327, ~32 sigma headroom

// native clang vectors (nontemporal builtins reject HIP_vector_type classes)
typedef int v2i __attribute__((ext_vector_type(2)));

__device__ inline __half2 h2_shfl_xor(__half2 v, int m) {
    int i = __shfl_xor(*reinterpret_cast<int*>(&v), m, 32);
    return *reinterpret_cast<__half2*>(&i);
}
__device__ inline __half2 u2h(unsigned int u) {
    return *reinterpret_cast<__half2*>(&u);
}

// ---------- multisplit, 2-pass: hist+reserve, then re-read & place ----------
__global__ __launch_bounds__(1024) void k_msplit3(const int* __restrict__ eidx,
                                                  int* __restrict__ binCursor,
                                                  unsigned int* __restrict__ binned,
                                                  int* __restrict__ ovfCnt,
                                                  v2i* __restrict__ ovf,
                                                  int E, int NB, int cap) {
    __shared__ int hist[256], base[256];
    __shared__ int stF;
    int t = threadIdx.x;
    if (t == 0) {           // int32 vs int64 detect (odd words of first 64 i64 all 0)
        int o = 0;
        for (int j = 1; j < 128; j += 2) o |= eidx[j];
        stF = (o == 0) ? 2 : 1;
    }
    __syncthreads();
    int st = stF;
    int ntiles = (E + MS_TILE - 1) / MS_TILE;

    for (int tile = blockIdx.x; tile < ntiles; tile += gridDim.x) {
        int e0 = tile * MS_TILE;
        int e1 = min(e0 + MS_TILE, E);

        if (t < 256) hist[t] = 0;
        __syncthreads();
        for (int e = e0 + t; e < e1; e += 1024) {
            int d = (st == 2) ? ((const v2i*)eidx)[E + e].x : eidx[E + e];
            atomicAdd(&hist[d >> BSH], 1);
        }
        __syncthreads();
        if (t < NB && hist[t] > 0) base[t] = atomicAdd(&binCursor[t], hist[t]);
        __syncthreads();
        if (t < 256) hist[t] = 0;   // reuse as rank counters
        __syncthreads();
        for (int e = e0 + t; e < e1; e += 1024) {
            int s, d;
            if (st == 2) {
                s = ((const v2i*)eidx)[e].x;
                d = ((const v2i*)eidx)[E + e].x;
            } else {
                s = eidx[e];
                d = eidx[E + e];
            }
            int b = d >> BSH;
            int r = atomicAdd(&hist[b], 1);
            int local = base[b] + r;
            if (local < cap) {
                binned[(size_t)b * cap + local] =
                    ((unsigned int)s << BSH) | (unsigned int)(d & (BINSZ - 1));
            } else {
                int o = atomicAdd(ovfCnt, 1);
                if (o < OVF_CAP) ovf[o] = (v2i){s, d};
            }
        }
        __syncthreads();
    }
}

// ---------- exclusive scan of bin totals -> binBase ----------
__global__ __launch_bounds__(512) void k_binscan(const int* __restrict__ binCursor,
                                                 int* __restrict__ binBase,
                                                 int NB, int cap) {
    __shared__ int sh[512];
    int t = threadIdx.x;
    int v = (t < NB) ? min(binCursor[t], cap) : 0;
    sh[t] = v;
    __syncthreads();
    for (int d = 1; d < 512; d <<= 1) {
        int add = (t >= d) ? sh[t - d] : 0;
        __syncthreads();
        sh[t] += add;
        __syncthreads();
    }
    if (t < NB) binBase[t] = sh[t] - v;
}

// ---------- fused fill: hist + scan -> offsets/dinv/cursor; stage + flush csr ----------
__global__ __launch_bounds__(512) void k_fillA(const unsigned int* __restrict__ binned,
                                               const int* __restrict__ binCursor,
                                               const int* __restrict__ binBase,
                                               int* __restrict__ offsets,
                                               int* __restrict__ cursor,
                                               float* __restrict__ dinv,
                                               int* __restrict__ csr,
                                               int cap, int N) {
    __shared__ int hist[BINSZ], scanS[BINSZ], curL[BINSZ];
    __shared__ unsigned int stage[CAPL];
    int b = blockIdx.x;
    int t = threadIdx.x;
    int g0 = b << BSH;
    int g = g0 + t;
    int n = min(binCursor[b], cap);
    const unsigned int* p = binned + (size_t)b * cap;

    hist[t] = 0;
    __syncthreads();
    for (int i = t; i < n; i += 512)
        atomicAdd(&hist[p[i] & (BINSZ - 1)], 1);
    __syncthreads();
    int h = hist[t];
    scanS[t] = h;
    __syncthreads();
    for (int d = 1; d < 512; d <<= 1) {
        int add = (t >= d) ? scanS[t - d] : 0;
        __syncthreads();
        scanS[t] += add;
        __syncthreads();
    }
    int excl = scanS[t] - h;
    int gbase = binBase[b];
    if (g < N) {
        offsets[g] = gbase + excl;
        dinv[g] = rsqrtf((float)(h + 1));
    }
    if (t == 511) offsets[min(g0 + BINSZ, N)] = gbase + scanS[511];  // race-benign dup

    curL[t] = excl;
    __syncthreads();
    int nl = min(n, CAPL);
    for (int i = t; i < nl; i += 512) {
        unsigned int w = p[i];
        int pos = atomicAdd(&curL[w & (BINSZ - 1)], 1);
        if (pos < CAPL) stage[pos] = w >> BSH;
    }
    __syncthreads();
    if (g < N) cursor[g] = gbase + curL[t];     // final positions (ovf valve)
    for (int i = t; i < nl; i += 512)
        csr[gbase + i] = (int)stage[i];         // coalesced flush
    __syncthreads();
    for (int i = CAPL + t; i < n; i += 512) {   // dead by construction
        unsigned int w = p[i];
        int pos = atomicAdd(&cursor[g0 + (int)(w & (BINSZ - 1))], 1);
        csr[pos] = (int)(w >> BSH);
    }
}

// ---------- drain overflow valve (normally 0 edges) ----------
__global__ void k_ovf(const int* __restrict__ ovfCnt, const v2i* __restrict__ ovf,
                      int* __restrict__ cursor, int* __restrict__ csr) {
    int n = min(*ovfCnt, OVF_CAP);
    for (int i = threadIdx.x; i < n; i += 256) {
        v2i e = ovf[i];
        int pos = atomicAdd(&cursor[e.y], 1);
        csr[pos] = e.x;
    }
}

// ---------- GEMM1: h1' = (x @ W1) * dinv[row], fp16-packed [N,32] __half2 ----------
__global__ __launch_bounds__(256) void k_gemm1t(const float* __restrict__ x,
                                                const float* __restrict__ W,
                                                const float* __restrict__ dinv,
                                                __half2* __restrict__ h1, int N) {
    __shared__ __half xsT[DIM_IN * 64];     // [k][row] transposed tile, 16KB fp16
    __shared__ float Ws[DIM_IN * DIM_HID];  // [k][col], 32KB
    int t = threadIdx.x;
    int row0 = blockIdx.x * 64;

#pragma unroll
    for (int i = 0; i < 8; i++)
        ((float4*)Ws)[t + 256 * i] = ((const float4*)W)[t + 256 * i];

#pragma unroll
    for (int i = 0; i < 8; i++) {
        int idx = t * 8 + i;
        int r = idx >> 5;
        int kc = idx & 31;
        int row = row0 + r;
        float4 v = (row < N) ? ((const float4*)(x + (size_t)row * DIM_IN))[kc]
                             : make_float4(0.f, 0.f, 0.f, 0.f);
        xsT[(4 * kc + 0) * 64 + r] = __float2half(v.x);
        xsT[(4 * kc + 1) * 64 + r] = __float2half(v.y);
        xsT[(4 * kc + 2) * 64 + r] = __float2half(v.z);
        xsT[(4 * kc + 3) * 64 + r] = __float2half(v.w);
    }
    __syncthreads();

    int c = t & 15;
    int r = t >> 4;
    float acc[4][4] = {};

#pragma unroll 4
    for (int k = 0; k < DIM_IN; k++) {
        __half2 xh01 = *(const __half2*)&xsT[k * 64 + 4 * r];
        __half2 xh23 = *(const __half2*)&xsT[k * 64 + 4 * r + 2];
        float2 x01 = __half22float2(xh01);
        float2 x23 = __half22float2(xh23);
        float4 wb = *(const float4*)&Ws[k * DIM_HID + 4 * c];
        float xi[4] = {x01.x, x01.y, x23.x, x23.y};
#pragma unroll
        for (int i = 0; i < 4; i++) {
            acc[i][0] = fmaf(xi[i], wb.x, acc[i][0]);
            acc[i][1] = fmaf(xi[i], wb.y, acc[i][1]);
            acc[i][2] = fmaf(xi[i], wb.z, acc[i][2]);
            acc[i][3] = fmaf(xi[i], wb.w, acc[i][3]);
        }
    }

#pragma unroll
    for (int i = 0; i < 4; i++) {
        int row = row0 + 4 * r + i;
        if (row < N) {
            float d = dinv[row];
            h1[(size_t)row * 32 + 2 * c] = __floats2half2_rn(acc[i][0] * d, acc[i][1] * d);
            h1[(size_t)row * 32 + 2 * c + 1] = __floats2half2_rn(acc[i][2] * d, acc[i][3] * d);
        }
    }
}

// ---------- agg1: g = relu(di*(sum h1'[src] + h1'[node]) + b1); h2' = (g@W2)*di ----------
// R19: half-wave per node organized as 4 edge-slots x 8 feature-lanes; each
// edge's 128B row fetched as 8 x dwordx4 (requests/edge 32 -> 8; attacks the
// request-rate limit evidenced by 156MB pinned FETCH at only 30% HBM BW).
__global__ __launch_bounds__(256) void k_agg1(const __half2* __restrict__ h1,
                                              const int* __restrict__ csr,
                                              const int* __restrict__ offsets,
                                              const float* __restrict__ dinv,
                                              const float* __restrict__ b1,
                                              const float* __restrict__ W2,
                                              float4* __restrict__ h2, int N) {
    __shared__ float W2s[DIM_HID * 3];
    __shared__ float b1s[DIM_HID];
    int t = threadIdx.x;
    if (t < DIM_HID * 3) W2s[t] = W2[t];
    if (t < DIM_HID) b1s[t] = b1[t];
    __syncthreads();

    int hl = t & 31;
    int slot = hl >> 3;      // 0..3 edge slot
    int f8 = hl & 7;         // feature octet (features 8*f8 .. 8*f8+7)
    int node = blockIdx.x * 8 + (t >> 5);
    if (node >= N) return;

    const uint4* h1q = (const uint4*)h1;   // row = 8 x uint4 (128B)
    float di = dinv[node];
    int beg = offsets[node], end = offsets[node + 1];

    __half2 a0, a1, a2, a3;
    if (slot == 0) {                       // self-loop (pre-scaled)
        uint4 v = h1q[(size_t)node * 8 + f8];
        a0 = u2h(v.x); a1 = u2h(v.y); a2 = u2h(v.z); a3 = u2h(v.w);
    } else {
        a0 = a1 = a2 = a3 = __floats2half2_rn(0.f, 0.f);
    }

    for (int base = beg; base < end; base += 32) {
        int cnt = min(32, end - base);
        int sidx = (hl < cnt) ? csr[base + hl] : 0;
        int iters = (cnt + 3) >> 2;
        for (int j = 0; j < iters; j++) {
            int idx = 4 * j + slot;
            int s = __shfl(sidx, idx, 32);
            if (idx < cnt) {
                uint4 v = h1q[(size_t)s * 8 + f8];
                a0 = __hadd2(a0, u2h(v.x));
                a1 = __hadd2(a1, u2h(v.y));
                a2 = __hadd2(a2, u2h(v.z));
                a3 = __hadd2(a3, u2h(v.w));
            }
        }
    }

    // reduce across the 4 edge-slots (lanes hl^8, hl^16 within the half-wave)
    a0 = __hadd2(a0, h2_shfl_xor(a0, 8));  a0 = __hadd2(a0, h2_shfl_xor(a0, 16));
    a1 = __hadd2(a1, h2_shfl_xor(a1, 8));  a1 = __hadd2(a1, h2_shfl_xor(a1, 16));
    a2 = __hadd2(a2, h2_shfl_xor(a2, 8));  a2 = __hadd2(a2, h2_shfl_xor(a2, 16));
    a3 = __hadd2(a3, h2_shfl_xor(a3, 8));  a3 = __hadd2(a3, h2_shfl_xor(a3, 16));

    if (slot == 0) {                       // epilogue on 8 lanes per node
        float2 f0 = __half22float2(a0), f1 = __half22float2(a1);
        float2 f2 = __half22float2(a2), f3 = __half22float2(a3);
        float acc[8] = {f0.x, f0.y, f1.x, f1.y, f2.x, f2.y, f3.x, f3.y};
        float v0 = 0.f, v1 = 0.f, v2 = 0.f;
#pragma unroll
        for (int k = 0; k < 8; k++) {
            int f = 8 * f8 + k;
            float gg = fmaxf(fmaf(acc[k], di, b1s[f]), 0.f);
            v0 = fmaf(gg, W2s[f * 3 + 0], v0);
            v1 = fmaf(gg, W2s[f * 3 + 1], v1);
            v2 = fmaf(gg, W2s[f * 3 + 2], v2);
        }
#pragma unroll
        for (int off = 4; off > 0; off >>= 1) {
            v0 += __shfl_xor(v0, off, 8);
            v1 += __shfl_xor(v1, off, 8);
            v2 += __shfl_xor(v2, off, 8);
        }
        if (f8 == 0) h2[node] = make_float4(v0 * di, v1 * di, v2 * di, 0.f);
    }
}

// ---------- agg2: out = di*(sum h2'[src] + h2'[node]) + b2 ----------
__global__ __launch_bounds__(256) void k_agg2(const float4* __restrict__ h2,
                                              const int* __restrict__ csr,
                                              const int* __restrict__ offsets,
                                              const float* __restrict__ dinv,
                                              const float* __restrict__ b2,
                                              float* __restrict__ out, int N) {
    int t = threadIdx.x;
    int l = t & 7;
    int node = blockIdx.x * 32 + (t >> 3);
    if (node >= N) return;

    float di = dinv[node];
    int beg = offsets[node], end = offsets[node + 1];
    float a0 = 0.f, a1 = 0.f, a2 = 0.f;
    for (int e = beg + l; e < end; e += 8) {
        float4 h = h2[csr[e]];
        a0 += h.x;
        a1 += h.y;
        a2 += h.z;
    }
#pragma unroll
    for (int off = 4; off > 0; off >>= 1) {
        a0 += __shfl_xor(a0, off, 8);
        a1 += __shfl_xor(a1, off, 8);
        a2 += __shfl_xor(a2, off, 8);
    }
    if (l == 0) {
        float4 hs = h2[node];
        out[(size_t)node * 3 + 0] = fmaf(a0 + hs.x, di, b2[0]);
        out[(size_t)node * 3 + 1] = fmaf(a1 + hs.y, di, b2[1]);
        out[(size_t)node * 3 + 2] = fmaf(a2 + hs.z, di, b2[2]);
    }
}

extern "C" void kernel_launch(void* const* d_in, const int* in_sizes, int n_in,
                              void* d_out, int out_size, void* d_ws, size_t ws_size,
                              hipStream_t stream) {
    const float* x = (const float*)d_in[0];
    const int* eidx = (const int*)d_in[1];
    const float* W1 = (const float*)d_in[2];
    const float* b1 = (const float*)d_in[3];
    const float* W2 = (const float*)d_in[4];
    const float* b2 = (const float*)d_in[5];
    float* out = (float*)d_out;

    const int N = in_sizes[0] / DIM_IN;     // 100000
    const int E = in_sizes[1] / 2;          // 3200000
    const int NB = (N + BINSZ - 1) >> BSH;  // 196 bins of 512 nodes

    char* w = (char*)d_ws;
    size_t off = 0;
    auto carve = [&](size_t bytes) -> char* {
        char* p = w + off;
        off += (bytes + 255) & ~(size_t)255;
        return p;
    };
    int* offsets = (int*)carve((size_t)(N + 1) * 4);
    int* cursor = (int*)carve((size_t)N * 4);
    float* dinv = (float*)carve((size_t)N * 4);
    int* csr = (int*)carve((size_t)E * 4);
    int* binCursor = (int*)carve(MAXNB * 4);
    int* ovfCnt = (int*)carve(16);
    v2i* ovf = (v2i*)carve((size_t)OVF_CAP * 8);
    int* binBase = (int*)carve(MAXNB * 4);
    float4* h2 = (float4*)carve((size_t)N * 16);

    // uni region: packed binned words (msplit..fillA), then aliased by fp16 h1'.
    size_t h1_bytes = (size_t)N * DIM_HID * 2;
    int capDes = E / NB + E / NB / 16 + 256;     // mean + margin; < CAPL by construction
    size_t binned_des = (size_t)NB * capDes * 4;
    size_t uni_avail = (ws_size > off + 256) ? (ws_size - off - 256) : h1_bytes;
    size_t uni_bytes = binned_des > h1_bytes ? binned_des : h1_bytes;
    if (uni_bytes > uni_avail) uni_bytes = uni_avail > h1_bytes ? uni_avail : h1_bytes;
    char* uni = carve(uni_bytes);
    unsigned int* binned = (unsigned int*)uni;
    __half2* h1 = (__half2*)uni;        // aliased: valid only after k_fillA
    int cap = (int)(uni_bytes / ((size_t)NB * 4));
    if (cap > capDes) cap = capDes;
    if (cap > CAPL) cap = CAPL;         // keep the fillA stage invariant

    (void)hipMemsetAsync(binCursor, 0, MAXNB * 4 + 256, stream);  // binCursor + ovfCnt

    int ntiles = (E + MS_TILE - 1) / MS_TILE;
    k_msplit3<<<ntiles, 1024, 0, stream>>>(eidx, binCursor, binned, ovfCnt, ovf,
                                           E, NB, cap);
    k_binscan<<<1, 512, 0, stream>>>(binCursor, binBase, NB, cap);
    k_fillA<<<NB, 512, 0, stream>>>(binned, binCursor, binBase, offsets, cursor,
                                    dinv, csr, cap, N);
    k_ovf<<<1, 256, 0, stream>>>(ovfCnt, ovf, cursor, csr);

    k_gemm1t<<<(N + 63) / 64, 256, 0, stream>>>(x, W1, dinv, h1, N);
    k_agg1<<<(N + 7) / 8, 256, 0, stream>>>(h1, csr, offsets, dinv, b1, W2, h2, N);
    k_agg2<<<(N + 31) / 32, 256, 0, stream>>>(h2, csr, offsets, dinv, b2, out, N);
}

// Round 20
// 167.139 us; speedup vs baseline: 1.3051x; 1.0458x over previous
//
#include <hip/hip_runtime.h>
#include <hip/hip_fp16.h>
#include <cstdint>
#include <cstddef>

#define DIM_IN 128
#define DIM_HID 64
#define MS_TILE 16384     // edges per multisplit tile; runs = MS_TILE/NB ~ 84 edges
#define OVF_CAP 32768     // overflow valve capacity (edges)
#define BSH 9             // bin shift: 512-node bins
#define BINSZ 512
#define MAXNB 512
#define CAPL 20480        // LDS stage (80KB); bin mean 16327, ~32 sigma headroom

// native clang vectors (nontemporal builtins reject HIP_vector_type classes)
typedef int v2i __attribute__((ext_vector_type(2)));

__device__ inline __half2 h2_shfl_xor(__half2 v, int m) {
    int i = __shfl_xor(*reinterpret_cast<int*>(&v), m, 32);
    return *reinterpret_cast<__half2*>(&i);
}
__device__ inline __half2 u2h(unsigned int u) {
    return *reinterpret_cast<__half2*>(&u);
}

// ---------- multisplit, 2-pass: hist+reserve, then re-read & place ----------
__global__ __launch_bounds__(1024) void k_msplit3(const int* __restrict__ eidx,
                                                  int* __restrict__ binCursor,
                                                  unsigned int* __restrict__ binned,
                                                  int* __restrict__ ovfCnt,
                                                  v2i* __restrict__ ovf,
                                                  int E, int NB, int cap) {
    __shared__ int hist[256], base[256];
    __shared__ int stF;
    int t = threadIdx.x;
    if (t == 0) {           // int32 vs int64 detect (odd words of first 64 i64 all 0)
        int o = 0;
        for (int j = 1; j < 128; j += 2) o |= eidx[j];
        stF = (o == 0) ? 2 : 1;
    }
    __syncthreads();
    int st = stF;
    int ntiles = (E + MS_TILE - 1) / MS_TILE;

    for (int tile = blockIdx.x; tile < ntiles; tile += gridDim.x) {
        int e0 = tile * MS_TILE;
        int e1 = min(e0 + MS_TILE, E);

        if (t < 256) hist[t] = 0;
        __syncthreads();
        for (int e = e0 + t; e < e1; e += 1024) {
            int d = (st == 2) ? ((const v2i*)eidx)[E + e].x : eidx[E + e];
            atomicAdd(&hist[d >> BSH], 1);
        }
        __syncthreads();
        if (t < NB && hist[t] > 0) base[t] = atomicAdd(&binCursor[t], hist[t]);
        __syncthreads();
        if (t < 256) hist[t] = 0;   // reuse as rank counters
        __syncthreads();
        for (int e = e0 + t; e < e1; e += 1024) {
            int s, d;
            if (st == 2) {
                s = ((const v2i*)eidx)[e].x;
                d = ((const v2i*)eidx)[E + e].x;
            } else {
                s = eidx[e];
                d = eidx[E + e];
            }
            int b = d >> BSH;
            int r = atomicAdd(&hist[b], 1);
            int local = base[b] + r;
            if (local < cap) {
                binned[(size_t)b * cap + local] =
                    ((unsigned int)s << BSH) | (unsigned int)(d & (BINSZ - 1));
            } else {
                int o = atomicAdd(ovfCnt, 1);
                if (o < OVF_CAP) ovf[o] = (v2i){s, d};
            }
        }
        __syncthreads();
    }
}

// ---------- fused fill: bin prefix (in-block) + hist + scan -> offsets/dinv/
// cursor; stage + flush csr.  R20: k_binscan launch folded in (one wave
// recomputes the <=196-bin exclusive prefix -- cheaper than a dispatch).
__global__ __launch_bounds__(512) void k_fillA(const unsigned int* __restrict__ binned,
                                               const int* __restrict__ binCursor,
                                               int* __restrict__ offsets,
                                               int* __restrict__ cursor,
                                               float* __restrict__ dinv,
                                               int* __restrict__ csr,
                                               int cap, int NB, int N) {
    __shared__ int hist[BINSZ], scanS[BINSZ], curL[BINSZ];
    __shared__ unsigned int stage[CAPL];
    __shared__ int gbaseS;
    int b = blockIdx.x;
    int t = threadIdx.x;
    int g0 = b << BSH;
    int g = g0 + t;
    int n = min(binCursor[b], cap);
    const unsigned int* p = binned + (size_t)b * cap;

    if (t < 64) {           // wave 0: exclusive prefix of bins [0,b)
        int acc = 0;
        for (int i = t; i < b; i += 64) acc += min(binCursor[i], cap);
#pragma unroll
        for (int off = 32; off > 0; off >>= 1) acc += __shfl_xor(acc, off, 64);
        if (t == 0) gbaseS = acc;
    }
    hist[t] = 0;
    __syncthreads();
    for (int i = t; i < n; i += 512)
        atomicAdd(&hist[p[i] & (BINSZ - 1)], 1);
    __syncthreads();
    int h = hist[t];
    scanS[t] = h;
    __syncthreads();
    for (int d = 1; d < 512; d <<= 1) {
        int add = (t >= d) ? scanS[t - d] : 0;
        __syncthreads();
        scanS[t] += add;
        __syncthreads();
    }
    int excl = scanS[t] - h;
    int gbase = gbaseS;
    if (g < N) {
        offsets[g] = gbase + excl;
        dinv[g] = rsqrtf((float)(h + 1));
    }
    if (t == 511) offsets[min(g0 + BINSZ, N)] = gbase + scanS[511];  // race-benign dup

    curL[t] = excl;
    __syncthreads();
    int nl = min(n, CAPL);
    for (int i = t; i < nl; i += 512) {
        unsigned int w = p[i];
        int pos = atomicAdd(&curL[w & (BINSZ - 1)], 1);
        if (pos < CAPL) stage[pos] = w >> BSH;
    }
    __syncthreads();
    if (g < N) cursor[g] = gbase + curL[t];     // final positions (ovf valve)
    for (int i = t; i < nl; i += 512)
        csr[gbase + i] = (int)stage[i];         // coalesced flush
    __syncthreads();
    for (int i = CAPL + t; i < n; i += 512) {   // dead by construction
        unsigned int w = p[i];
        int pos = atomicAdd(&cursor[g0 + (int)(w & (BINSZ - 1))], 1);
        csr[pos] = (int)(w >> BSH);
    }
}

// ---------- GEMM1: h1' = (x @ W1) * dinv[row], fp16-packed [N,32] __half2 ----------
// R20: trailing block drains the (always-empty) overflow valve -- k_ovf launch
// deleted; ordering preserved (gemm1t runs after fillA, before agg1).
__global__ __launch_bounds__(256) void k_gemm1t(const float* __restrict__ x,
                                                const float* __restrict__ W,
                                                const float* __restrict__ dinv,
                                                __half2* __restrict__ h1, int N,
                                                const int* __restrict__ ovfCnt,
                                                const v2i* __restrict__ ovf,
                                                int* __restrict__ cursor,
                                                int* __restrict__ csr) {
    int t = threadIdx.x;
    if (blockIdx.x == gridDim.x - 1) {          // overflow drain block
        int n = min(*ovfCnt, OVF_CAP);
        for (int i = t; i < n; i += 256) {
            v2i e = ovf[i];
            int pos = atomicAdd(&cursor[e.y], 1);
            csr[pos] = e.x;
        }
        return;
    }

    __shared__ __half xsT[DIM_IN * 64];     // [k][row] transposed tile, 16KB fp16
    __shared__ float Ws[DIM_IN * DIM_HID];  // [k][col], 32KB
    int row0 = blockIdx.x * 64;

#pragma unroll
    for (int i = 0; i < 8; i++)
        ((float4*)Ws)[t + 256 * i] = ((const float4*)W)[t + 256 * i];

#pragma unroll
    for (int i = 0; i < 8; i++) {
        int idx = t * 8 + i;
        int r = idx >> 5;
        int kc = idx & 31;
        int row = row0 + r;
        float4 v = (row < N) ? ((const float4*)(x + (size_t)row * DIM_IN))[kc]
                             : make_float4(0.f, 0.f, 0.f, 0.f);
        xsT[(4 * kc + 0) * 64 + r] = __float2half(v.x);
        xsT[(4 * kc + 1) * 64 + r] = __float2half(v.y);
        xsT[(4 * kc + 2) * 64 + r] = __float2half(v.z);
        xsT[(4 * kc + 3) * 64 + r] = __float2half(v.w);
    }
    __syncthreads();

    int c = t & 15;
    int r = t >> 4;
    float acc[4][4] = {};

#pragma unroll 4
    for (int k = 0; k < DIM_IN; k++) {
        __half2 xh01 = *(const __half2*)&xsT[k * 64 + 4 * r];
        __half2 xh23 = *(const __half2*)&xsT[k * 64 + 4 * r + 2];
        float2 x01 = __half22float2(xh01);
        float2 x23 = __half22float2(xh23);
        float4 wb = *(const float4*)&Ws[k * DIM_HID + 4 * c];
        float xi[4] = {x01.x, x01.y, x23.x, x23.y};
#pragma unroll
        for (int i = 0; i < 4; i++) {
            acc[i][0] = fmaf(xi[i], wb.x, acc[i][0]);
            acc[i][1] = fmaf(xi[i], wb.y, acc[i][1]);
            acc[i][2] = fmaf(xi[i], wb.z, acc[i][2]);
            acc[i][3] = fmaf(xi[i], wb.w, acc[i][3]);
        }
    }

#pragma unroll
    for (int i = 0; i < 4; i++) {
        int row = row0 + 4 * r + i;
        if (row < N) {
            float d = dinv[row];
            h1[(size_t)row * 32 + 2 * c] = __floats2half2_rn(acc[i][0] * d, acc[i][1] * d);
            h1[(size_t)row * 32 + 2 * c + 1] = __floats2half2_rn(acc[i][2] * d, acc[i][3] * d);
        }
    }
}

// ---------- agg1: g = relu(di*(sum h1'[src] + h1'[node]) + b1); h2' = (g@W2)*di ----------
// R20: __launch_bounds__(256,8) requests full residency (R19 occupancy 63% at
// 20 VGPR -> more waves = more outstanding misses) + 2-deep load batching.
__global__ __launch_bounds__(256, 8) void k_agg1(const __half2* __restrict__ h1,
                                                 const int* __restrict__ csr,
                                                 const int* __restrict__ offsets,
                                                 const float* __restrict__ dinv,
                                                 const float* __restrict__ b1,
                                                 const float* __restrict__ W2,
                                                 float4* __restrict__ h2, int N) {
    __shared__ float W2s[DIM_HID * 3];
    __shared__ float b1s[DIM_HID];
    int t = threadIdx.x;
    if (t < DIM_HID * 3) W2s[t] = W2[t];
    if (t < DIM_HID) b1s[t] = b1[t];
    __syncthreads();

    int hl = t & 31;
    int slot = hl >> 3;      // 0..3 edge slot
    int f8 = hl & 7;         // feature octet (features 8*f8 .. 8*f8+7)
    int node = blockIdx.x * 8 + (t >> 5);
    if (node >= N) return;

    const uint4* h1q = (const uint4*)h1;   // row = 8 x uint4 (128B)
    float di = dinv[node];
    int beg = offsets[node], end = offsets[node + 1];

    __half2 a0, a1, a2, a3;
    if (slot == 0) {                       // self-loop (pre-scaled)
        uint4 v = h1q[(size_t)node * 8 + f8];
        a0 = u2h(v.x); a1 = u2h(v.y); a2 = u2h(v.z); a3 = u2h(v.w);
    } else {
        a0 = a1 = a2 = a3 = __floats2half2_rn(0.f, 0.f);
    }

    for (int base = beg; base < end; base += 32) {
        int cnt = min(32, end - base);
        int sidx = (hl < cnt) ? csr[base + hl] : 0;
        int iters = (cnt + 3) >> 2;
        int j = 0;
        for (; j + 1 < iters; j += 2) {    // 2-deep: both gathers in flight
            int i0 = 4 * j + slot;
            int i1 = i0 + 4;
            int s0 = __shfl(sidx, i0, 32);
            int s1 = __shfl(sidx, i1, 32);
            bool p0 = i0 < cnt, p1 = i1 < cnt;
            uint4 v0 = p0 ? h1q[(size_t)s0 * 8 + f8] : make_uint4(0, 0, 0, 0);
            uint4 v1 = p1 ? h1q[(size_t)s1 * 8 + f8] : make_uint4(0, 0, 0, 0);
            a0 = __hadd2(a0, u2h(v0.x)); a1 = __hadd2(a1, u2h(v0.y));
            a2 = __hadd2(a2, u2h(v0.z)); a3 = __hadd2(a3, u2h(v0.w));
            a0 = __hadd2(a0, u2h(v1.x)); a1 = __hadd2(a1, u2h(v1.y));
            a2 = __hadd2(a2, u2h(v1.z)); a3 = __hadd2(a3, u2h(v1.w));
        }
        if (j < iters) {
            int i0 = 4 * j + slot;
            int s0 = __shfl(sidx, i0, 32);
            if (i0 < cnt) {
                uint4 v = h1q[(size_t)s0 * 8 + f8];
                a0 = __hadd2(a0, u2h(v.x)); a1 = __hadd2(a1, u2h(v.y));
                a2 = __hadd2(a2, u2h(v.z)); a3 = __hadd2(a3, u2h(v.w));
            }
        }
    }

    // reduce across the 4 edge-slots (lanes hl^8, hl^16 within the half-wave)
    a0 = __hadd2(a0, h2_shfl_xor(a0, 8));  a0 = __hadd2(a0, h2_shfl_xor(a0, 16));
    a1 = __hadd2(a1, h2_shfl_xor(a1, 8));  a1 = __hadd2(a1, h2_shfl_xor(a1, 16));
    a2 = __hadd2(a2, h2_shfl_xor(a2, 8));  a2 = __hadd2(a2, h2_shfl_xor(a2, 16));
    a3 = __hadd2(a3, h2_shfl_xor(a3, 8));  a3 = __hadd2(a3, h2_shfl_xor(a3, 16));

    if (slot == 0) {                       // epilogue on 8 lanes per node
        float2 f0 = __half22float2(a0), f1 = __half22float2(a1);
        float2 f2 = __half22float2(a2), f3 = __half22float2(a3);
        float acc[8] = {f0.x, f0.y, f1.x, f1.y, f2.x, f2.y, f3.x, f3.y};
        float v0 = 0.f, v1 = 0.f, v2 = 0.f;
#pragma unroll
        for (int k = 0; k < 8; k++) {
            int f = 8 * f8 + k;
            float gg = fmaxf(fmaf(acc[k], di, b1s[f]), 0.f);
            v0 = fmaf(gg, W2s[f * 3 + 0], v0);
            v1 = fmaf(gg, W2s[f * 3 + 1], v1);
            v2 = fmaf(gg, W2s[f * 3 + 2], v2);
        }
#pragma unroll
        for (int off = 4; off > 0; off >>= 1) {
            v0 += __shfl_xor(v0, off, 8);
            v1 += __shfl_xor(v1, off, 8);
            v2 += __shfl_xor(v2, off, 8);
        }
        if (f8 == 0) h2[node] = make_float4(v0 * di, v1 * di, v2 * di, 0.f);
    }
}

// ---------- agg2: out = di*(sum h2'[src] + h2'[node]) + b2 ----------
__global__ __launch_bounds__(256) void k_agg2(const float4* __restrict__ h2,
                                              const int* __restrict__ csr,
                                              const int* __restrict__ offsets,
                                              const float* __restrict__ dinv,
                                              const float* __restrict__ b2,
                                              float* __restrict__ out, int N) {
    int t = threadIdx.x;
    int l = t & 7;
    int node = blockIdx.x * 32 + (t >> 3);
    if (node >= N) return;

    float di = dinv[node];
    int beg = offsets[node], end = offsets[node + 1];
    float a0 = 0.f, a1 = 0.f, a2 = 0.f;
    for (int e = beg + l; e < end; e += 8) {
        float4 h = h2[csr[e]];
        a0 += h.x;
        a1 += h.y;
        a2 += h.z;
    }
#pragma unroll
    for (int off = 4; off > 0; off >>= 1) {
        a0 += __shfl_xor(a0, off, 8);
        a1 += __shfl_xor(a1, off, 8);
        a2 += __shfl_xor(a2, off, 8);
    }
    if (l == 0) {
        float4 hs = h2[node];
        out[(size_t)node * 3 + 0] = fmaf(a0 + hs.x, di, b2[0]);
        out[(size_t)node * 3 + 1] = fmaf(a1 + hs.y, di, b2[1]);
        out[(size_t)node * 3 + 2] = fmaf(a2 + hs.z, di, b2[2]);
    }
}

extern "C" void kernel_launch(void* const* d_in, const int* in_sizes, int n_in,
                              void* d_out, int out_size, void* d_ws, size_t ws_size,
                              hipStream_t stream) {
    const float* x = (const float*)d_in[0];
    const int* eidx = (const int*)d_in[1];
    const float* W1 = (const float*)d_in[2];
    const float* b1 = (const float*)d_in[3];
    const float* W2 = (const float*)d_in[4];
    const float* b2 = (const float*)d_in[5];
    float* out = (float*)d_out;

    const int N = in_sizes[0] / DIM_IN;     // 100000
    const int E = in_sizes[1] / 2;          // 3200000
    const int NB = (N + BINSZ - 1) >> BSH;  // 196 bins of 512 nodes

    char* w = (char*)d_ws;
    size_t off = 0;
    auto carve = [&](size_t bytes) -> char* {
        char* p = w + off;
        off += (bytes + 255) & ~(size_t)255;
        return p;
    };
    int* offsets = (int*)carve((size_t)(N + 1) * 4);
    int* cursor = (int*)carve((size_t)N * 4);
    float* dinv = (float*)carve((size_t)N * 4);
    int* csr = (int*)carve((size_t)E * 4);
    int* binCursor = (int*)carve(MAXNB * 4);
    int* ovfCnt = (int*)carve(16);
    v2i* ovf = (v2i*)carve((size_t)OVF_CAP * 8);
    float4* h2 = (float4*)carve((size_t)N * 16);

    // uni region: packed binned words (msplit..fillA), then aliased by fp16 h1'.
    size_t h1_bytes = (size_t)N * DIM_HID * 2;
    int capDes = E / NB + E / NB / 16 + 256;     // mean + margin; < CAPL by construction
    size_t binned_des = (size_t)NB * capDes * 4;
    size_t uni_avail = (ws_size > off + 256) ? (ws_size - off - 256) : h1_bytes;
    size_t uni_bytes = binned_des > h1_bytes ? binned_des : h1_bytes;
    if (uni_bytes > uni_avail) uni_bytes = uni_avail > h1_bytes ? uni_avail : h1_bytes;
    char* uni = carve(uni_bytes);
    unsigned int* binned = (unsigned int*)uni;
    __half2* h1 = (__half2*)uni;        // aliased: valid only after k_fillA
    int cap = (int)(uni_bytes / ((size_t)NB * 4));
    if (cap > capDes) cap = capDes;
    if (cap > CAPL) cap = CAPL;         // keep the fillA stage invariant

    (void)hipMemsetAsync(binCursor, 0, MAXNB * 4 + 256, stream);  // binCursor + ovfCnt

    int ntiles = (E + MS_TILE - 1) / MS_TILE;
    k_msplit3<<<ntiles, 1024, 0, stream>>>(eidx, binCursor, binned, ovfCnt, ovf,
                                           E, NB, cap);
    k_fillA<<<NB, 512, 0, stream>>>(binned, binCursor, offsets, cursor,
                                    dinv, csr, cap, NB, N);
    k_gemm1t<<<(N + 63) / 64 + 1, 256, 0, stream>>>(x, W1, dinv, h1, N,
                                                    ovfCnt, ovf, cursor, csr);
    k_agg1<<<(N + 7) / 8, 256, 0, stream>>>(h1, csr, offsets, dinv, b1, W2, h2, N);
    k_agg2<<<(N + 31) / 32, 256, 0, stream>>>(h2, csr, offsets, dinv, b2, out, N);
}